// Round 1
// 571.064 us; speedup vs baseline: 1.6969x; 1.6969x over previous
//
#include <hip/hip_runtime.h>

// KoopmanOperator via split-bf16 MFMA.
// Block = 16 batch rows, 4 waves (256 thr). Wave w owns output-dim tile [16w,16w+16).
// Weights held in VGPRs as MFMA B-fragments, split W = Whi + Wlo (bf16 each).
// Matvec: D = A*B + C with A = Y/H rows (M=16 batch rows), B = W^T, via
// mfma_f32_16x16x32_bf16, 3-product split (err ~2^-17, dt-damped in recurrence).
// y/h exchanged between phases through XOR-swizzled bf16 LDS (2-way conflicts max).
// Rotation + tanh stay exact f32; pairs (2i,2i+1) are adjacent lanes in C/D layout.

#define T_STEPS 256
#define DD 64
#define DT 0.01f

typedef __attribute__((ext_vector_type(8))) short short8;  // 8 bf16 = 4 VGPR (A/B frag)
typedef __attribute__((ext_vector_type(4))) float f32x4;   // C/D frag

#define MFMA_BF16(a, b, c) __builtin_amdgcn_mfma_f32_16x16x32_bf16((a), (b), (c), 0, 0, 0)

static __device__ __forceinline__ short bf16_rne(float f) {
    unsigned u = __float_as_uint(f);
    u += 0x7FFFu + ((u >> 16) & 1u);       // round-to-nearest-even
    return (short)(u >> 16);
}
static __device__ __forceinline__ float bf16_f32(short s) {
    return __uint_as_float(((unsigned)(unsigned short)s) << 16);
}

__global__ __launch_bounds__(256, 1) void koopman_mfma(
    const float* __restrict__ x,
    const float* __restrict__ W1, const float* __restrict__ b1,
    const float* __restrict__ W2, const float* __restrict__ b2,
    float* __restrict__ out)
{
    // bf16 hi/lo staging buffers: [16 rows][64 dims], row stride 128 B
    __shared__ short y_hi[16 * DD], y_lo[16 * DD];
    __shared__ short h_hi[16 * DD], h_lo[16 * DD];

    const int tid   = threadIdx.x;
    const int w     = tid >> 6;        // wave 0..3 = output-dim tile
    const int lane  = tid & 63;
    const int m     = lane & 15;       // A-frag row (batch) / C-frag col (dim)
    const int g     = lane >> 4;       // k-group; C-frag rows g*4..g*4+3
    const int row0  = g << 2;
    const int b0    = blockIdx.x << 4; // 16 batch rows per block
    const int dglob = (w << 4) + m;    // global dim this lane owns in C/D
    const bool even = ((lane & 1) == 0);

    // ---- Build weight B-fragments (hi/lo split), resident in VGPRs ----
    // B[k][n] = W[n][k]; lane: n = m (local dim), k = kt*32 + g*8 + e.
    short8 w1h[2], w1l[2], w2h[2], w2l[2];
    #pragma unroll
    for (int kt = 0; kt < 2; ++kt) {
        const float* p1 = W1 + (size_t)dglob * DD + (kt << 5) + (g << 3);
        const float* p2 = W2 + (size_t)dglob * DD + (kt << 5) + (g << 3);
        #pragma unroll
        for (int e = 0; e < 8; ++e) {
            float v1 = p1[e];
            short h1 = bf16_rne(v1);
            w1h[kt][e] = h1;
            w1l[kt][e] = bf16_rne(v1 - bf16_f32(h1));
            float v2 = p2[e];
            short h2 = bf16_rne(v2);
            w2h[kt][e] = h2;
            w2l[kt][e] = bf16_rne(v2 - bf16_f32(h2));
        }
    }
    const float b1r = b1[dglob];
    const float b2r = b2[dglob];

    // ---- Initial state: y0 = x[:,0,:] in C/D layout (4 rows per lane) ----
    float yv[4];
    size_t obase[4];
    #pragma unroll
    for (int r = 0; r < 4; ++r) {
        int row = row0 + r;
        yv[r] = x[((size_t)(b0 + row) * T_STEPS) * DD + dglob];
        obase[r] = ((size_t)(b0 + row) * T_STEPS) * DD + dglob;
    }

    // Write y (bf16 hi/lo) to LDS, XOR-swizzled: byte ^= (row&7)<<4
    #pragma unroll
    for (int r = 0; r < 4; ++r) {
        int row  = row0 + r;
        int byte = ((row << 7) + (dglob << 1)) ^ ((row & 7) << 4);
        short hs = bf16_rne(yv[r]);
        *(short*)((char*)y_hi + byte) = hs;
        *(short*)((char*)y_lo + byte) = bf16_rne(yv[r] - bf16_f32(hs));
    }
    __syncthreads();

    // A-frag loader: batch row = m, dims d0..d0+7 contiguous -> ds_read_b128
    auto ldfrag = [&](const short* base, int kt) -> short8 {
        int d0   = (kt << 5) + (g << 3);
        int byte = ((m << 7) + (d0 << 1)) ^ ((m & 7) << 4);
        return *(const short8*)((const char*)base + byte);
    };

    for (int t = 0; t < T_STEPS; ++t) {
        // ---- matvec1: a = Y W1^T (split-bf16, f32 accum) ----
        short8 ah0 = ldfrag(y_hi, 0), al0 = ldfrag(y_lo, 0);
        short8 ah1 = ldfrag(y_hi, 1), al1 = ldfrag(y_lo, 1);
        f32x4 acc0 = {0.f, 0.f, 0.f, 0.f};
        f32x4 acc1 = {0.f, 0.f, 0.f, 0.f};
        acc0 = MFMA_BF16(ah0, w1h[0], acc0);
        acc1 = MFMA_BF16(ah1, w1h[1], acc1);
        acc0 = MFMA_BF16(al0, w1h[0], acc0);
        acc1 = MFMA_BF16(al1, w1h[1], acc1);
        acc0 = MFMA_BF16(ah0, w1l[0], acc0);
        acc1 = MFMA_BF16(ah1, w1l[1], acc1);

        // ---- h = tanh(a + b1) in f32; stage to LDS as bf16 hi/lo ----
        #pragma unroll
        for (int r = 0; r < 4; ++r) {
            float a  = acc0[r] + acc1[r] + b1r;
            float ex = __expf(2.0f * a);
            float th = 1.0f - __fdividef(2.0f, ex + 1.0f);
            int row  = row0 + r;
            int byte = ((row << 7) + (dglob << 1)) ^ ((row & 7) << 4);
            short hs = bf16_rne(th);
            *(short*)((char*)h_hi + byte) = hs;
            *(short*)((char*)h_lo + byte) = bf16_rne(th - bf16_f32(hs));
        }
        __syncthreads();

        // ---- matvec2: p = H W2^T ----
        ah0 = ldfrag(h_hi, 0); al0 = ldfrag(h_lo, 0);
        ah1 = ldfrag(h_hi, 1); al1 = ldfrag(h_lo, 1);
        f32x4 pc0 = {0.f, 0.f, 0.f, 0.f};
        f32x4 pc1 = {0.f, 0.f, 0.f, 0.f};
        pc0 = MFMA_BF16(ah0, w2h[0], pc0);
        pc1 = MFMA_BF16(ah1, w2h[1], pc1);
        pc0 = MFMA_BF16(al0, w2h[0], pc0);
        pc1 = MFMA_BF16(al1, w2h[1], pc1);
        pc0 = MFMA_BF16(ah0, w2l[0], pc0);
        pc1 = MFMA_BF16(ah1, w2l[1], pc1);

        // ---- rotation update (exact f32); pairs = adjacent lanes in C/D ----
        #pragma unroll
        for (int r = 0; r < 4; ++r) {
            float p   = pc0[r] + pc1[r] + b2r;
            float p_o = __shfl_xor(p, 1, 64);
            float y_o = __shfl_xor(yv[r], 1, 64);
            float mu  = even ? p    : p_o;    // p[2i]
            float om  = even ? p_o  : p;      // p[2i+1]
            float yy0 = even ? yv[r] : y_o;   // y[2i]
            float yy1 = even ? y_o   : yv[r]; // y[2i+1]
            float ev  = __expf(DT * mu);
            float c   = __cosf(DT * om);
            float s   = __sinf(DT * om);
            // reference signs verbatim: n0 = e*(c*y0 - s*y1); n1 = e*(s*y0 - c*y1)
            float n = even ? ev * (c * yy0 - s * yy1)
                           : ev * (s * yy0 - c * yy1);
            yv[r] = n;
            out[obase[r] + ((size_t)t << 6)] = n;   // out[b][t][d]

            int row  = row0 + r;
            int byte = ((row << 7) + (dglob << 1)) ^ ((row & 7) << 4);
            short hs = bf16_rne(n);
            *(short*)((char*)y_hi + byte) = hs;
            *(short*)((char*)y_lo + byte) = bf16_rne(n - bf16_f32(hs));
        }
        __syncthreads();   // y_lds ready for next step
    }
}

extern "C" void kernel_launch(void* const* d_in, const int* in_sizes, int n_in,
                              void* d_out, int out_size, void* d_ws, size_t ws_size,
                              hipStream_t stream) {
    const float* x  = (const float*)d_in[0];
    const float* W1 = (const float*)d_in[1];
    const float* b1 = (const float*)d_in[2];
    const float* W2 = (const float*)d_in[3];
    const float* b2 = (const float*)d_in[4];
    float* out = (float*)d_out;

    dim3 grid(4096 / 16);   // 256 blocks = 1 per CU
    dim3 block(256);        // 4 waves: one 16-dim output tile each
    koopman_mfma<<<grid, block, 0, stream>>>(x, W1, b1, W2, b2, out);
}